// Round 1
// baseline (262.243 us; speedup 1.0000x reference)
//
#include <hip/hip_runtime.h>

// Problem constants (from reference)
constexpr int NN = 10000;     // nodes
constexpr int NE = 160000;    // edges
constexpr float EPSV = 1e-5f;
constexpr float INV3 = 0.57735026918962576f;   // 1/sqrt(3)
constexpr float ALPHA = 0.20412414523193152f;  // 1/sqrt(16+8)
constexpr int EPW = 8;        // edges per wave

__device__ __forceinline__ float bcastf(float v, int k) {
  return __int_as_float(__builtin_amdgcn_readlane(__float_as_int(v), k));
}

// One wave handles EPW consecutive edges: full MLP (64->relu->64 ; 64->576),
// tensor product via shfl_xor butterflies, atomic scatter into seg/cnt.
__global__ __launch_bounds__(256) void edge_kernel(
    const float* __restrict__ nf, const float* __restrict__ ef,
    const float* __restrict__ sh, const int* __restrict__ ei,
    const float* __restrict__ w1, const float* __restrict__ b1,
    const float* __restrict__ w2, const float* __restrict__ b2,
    float* __restrict__ seg, float* __restrict__ cnt,
    float* __restrict__ efout)
{
  const int lane = threadIdx.x & 63;
  const int wid  = threadIdx.x >> 6;
  const long ebase = (long)(blockIdx.x * 4 + wid) * EPW;
  if (ebase >= NE) return;

  // Load edge-feature rows (lane i holds feature i of each edge) + fused copy-out
  float x[EPW];
#pragma unroll
  for (int e = 0; e < EPW; ++e) x[e] = ef[(ebase + e) * 64 + lane];
#pragma unroll
  for (int e = 0; e < EPW; ++e) efout[(ebase + e) * 64 + lane] = x[e];

  // ---- MLP layer 1: h = relu(ef @ W1 + b1) ----
  const float b1l = b1[lane];
  float h[EPW];
#pragma unroll
  for (int e = 0; e < EPW; ++e) h[e] = b1l;
#pragma unroll 4
  for (int k = 0; k < 64; ++k) {
    float w1k = w1[k * 64 + lane];
#pragma unroll
    for (int e = 0; e < EPW; ++e) h[e] = fmaf(bcastf(x[e], k), w1k, h[e]);
  }
#pragma unroll
  for (int e = 0; e < EPW; ++e) h[e] = fmaxf(h[e], 0.0f);

  // ---- MLP layer 2: w = h @ W2 + b2 ; lane holds j = r*64+lane, r=0..8 ----
  float acc[9][EPW];
#pragma unroll
  for (int r = 0; r < 9; ++r) {
    float b2r = b2[r * 64 + lane];
#pragma unroll
    for (int e = 0; e < EPW; ++e) acc[r][e] = b2r;
  }
#pragma unroll 2
  for (int k = 0; k < 64; ++k) {
    const float* __restrict__ w2k = w2 + k * 576;
    float wv[9];
#pragma unroll
    for (int r = 0; r < 9; ++r) wv[r] = w2k[r * 64 + lane];
#pragma unroll
    for (int e = 0; e < EPW; ++e) {
      float hk = bcastf(h[e], k);
#pragma unroll
      for (int r = 0; r < 9; ++r) acc[r][e] = fmaf(hk, wv[r], acc[r][e]);
    }
  }

  // ---- Tensor product + scatter ----
  // j = r*64+lane mappings:
  //   r=0..3 : w00[u = r*4 + (lane>>4)][v = lane&15]
  //   r=4..5 : w11[u = (r-4)*4 + (lane>>4)][v = lane&15]
  //   r=6..7 : w01[u = (r-6)*8 + (lane>>3)][v8 = lane&7]
  //   r=8    : w10[u = lane>>3][v8 = lane&7]
  const int hi4 = lane >> 4;
  const int hi3 = lane >> 3;
  const int v16 = lane & 15;

  for (int e = 0; e < EPW; ++e) {
    const long eid = ebase + e;
    const int dst = ei[eid];        // edge_index[0]
    const int src = ei[NE + eid];   // edge_index[1]
    const float sh0 = sh[eid * 4 + 0];
    const float s1x = sh[eid * 4 + 1];
    const float s1y = sh[eid * 4 + 2];
    const float s1z = sh[eid * 4 + 3];
    const float* __restrict__ nfd = nf + (long)dst * 40;

    // out0[v] partial: sh0 * x0[u]*w00 + inv3 * (x1[u].sh1)*w11
    float p0 = 0.f;
#pragma unroll
    for (int r = 0; r < 4; ++r) p0 = fmaf(nfd[r * 4 + hi4], acc[r][e], p0);
    p0 *= sh0;
#pragma unroll
    for (int r = 4; r < 6; ++r) {
      int u = (r - 4) * 4 + hi4;
      float y = nfd[16 + u * 3 + 0] * s1x + nfd[16 + u * 3 + 1] * s1y +
                nfd[16 + u * 3 + 2] * s1z;
      p0 = fmaf(INV3 * y, acc[r][e], p0);
    }
    // z0[v8] partial: x0[u]*w01
    float pz = nfd[hi3] * acc[6][e] + nfd[8 + hi3] * acc[7][e];
    // t[v8][i] partial: x1[u][i]*w10
    float w10v = acc[8][e];
    float ptx = nfd[16 + hi3 * 3 + 0] * w10v;
    float pty = nfd[16 + hi3 * 3 + 1] * w10v;
    float ptz = nfd[16 + hi3 * 3 + 2] * w10v;

    // butterfly reductions over the u-groups
    p0 += __shfl_xor(p0, 16); p0 += __shfl_xor(p0, 32);
    pz  += __shfl_xor(pz, 8);  pz += __shfl_xor(pz, 16);  pz += __shfl_xor(pz, 32);
    ptx += __shfl_xor(ptx, 8); ptx += __shfl_xor(ptx, 16); ptx += __shfl_xor(ptx, 32);
    pty += __shfl_xor(pty, 8); pty += __shfl_xor(pty, 16); pty += __shfl_xor(pty, 32);
    ptz += __shfl_xor(ptz, 8); ptz += __shfl_xor(ptz, 16); ptz += __shfl_xor(ptz, 32);

    if (lane < 16) atomicAdd(seg + (long)src * 40 + v16, ALPHA * p0);
    if (lane < 8) {
      atomicAdd(seg + (long)src * 40 + 16 + lane * 3 + 0, ALPHA * (s1x * pz + sh0 * ptx));
      atomicAdd(seg + (long)src * 40 + 16 + lane * 3 + 1, ALPHA * (s1y * pz + sh0 * pty));
      atomicAdd(seg + (long)src * 40 + 16 + lane * 3 + 2, ALPHA * (s1z * pz + sh0 * ptz));
    }
    if (lane == 0) atomicAdd(cnt + src, 1.0f);
  }
}

// seg/cnt -> mean + residual; accumulate batchnorm stats
__global__ __launch_bounds__(256) void node_pass1(
    const float* __restrict__ seg, const float* __restrict__ cnt,
    const float* __restrict__ nf, float* __restrict__ pre,
    float* __restrict__ stats)
{
  __shared__ float ls[40];
  if (threadIdx.x < 40) ls[threadIdx.x] = 0.f;
  __syncthreads();
  int idx = blockIdx.x * blockDim.x + threadIdx.x;
  if (idx < NN * 40) {
    int n = idx / 40;
    int c = idx - n * 40;
    float cn = fmaxf(cnt[n], 1.f);
    float val = seg[idx] / cn + nf[idx];
    pre[idx] = val;
    if (c < 16) {
      atomicAdd(&ls[c], val);
      atomicAdd(&ls[16 + c], val * val);
    } else {
      int u = (c - 16) / 3;
      atomicAdd(&ls[32 + u], val * val);
    }
  }
  __syncthreads();
  if (threadIdx.x < 40) atomicAdd(&stats[threadIdx.x], ls[threadIdx.x]);
}

// apply normalization
__global__ __launch_bounds__(256) void node_pass2(
    const float* __restrict__ pre, const float* __restrict__ stats,
    const float* __restrict__ bnws, const float* __restrict__ bnbs,
    const float* __restrict__ bnwv, float* __restrict__ out)
{
  int idx = blockIdx.x * blockDim.x + threadIdx.x;
  if (idx >= NN * 40) return;
  int n = idx / 40;
  int c = idx - n * 40;
  float val = pre[idx];
  constexpr float invN = 1.0f / NN;
  if (c < 16) {
    float mu = stats[c] * invN;
    float var = stats[16 + c] * invN - mu * mu;
    out[idx] = (val - mu) * (rsqrtf(var + EPSV) * bnws[c]) + bnbs[c];
  } else {
    int u = (c - 16) / 3;
    float vn = stats[32 + u] * (invN / 3.0f);
    out[idx] = val * (rsqrtf(vn + EPSV) * bnwv[u]);
  }
}

extern "C" void kernel_launch(void* const* d_in, const int* in_sizes, int n_in,
                              void* d_out, int out_size, void* d_ws, size_t ws_size,
                              hipStream_t stream) {
  const float* nf   = (const float*)d_in[0];
  const float* ef   = (const float*)d_in[1];
  const float* sh   = (const float*)d_in[2];
  const int*   ei   = (const int*)d_in[3];
  const float* w1   = (const float*)d_in[4];
  const float* b1   = (const float*)d_in[5];
  const float* w2   = (const float*)d_in[6];
  const float* b2   = (const float*)d_in[7];
  const float* bnws = (const float*)d_in[8];
  const float* bnbs = (const float*)d_in[9];
  const float* bnwv = (const float*)d_in[10];

  float* out = (float*)d_out;                 // [NN*40] node out, then [NE*64] ef copy
  float* seg   = (float*)d_ws;                // NN*40
  float* cntb  = seg + (size_t)NN * 40;       // NN
  float* stats = cntb + NN;                   // 40
  float* pre   = stats + 40;                  // NN*40

  // zero accumulators (seg + cnt + stats are contiguous)
  hipMemsetAsync(d_ws, 0, ((size_t)NN * 40 + NN + 40) * sizeof(float), stream);

  const int blocks = (NE + 4 * EPW - 1) / (4 * EPW);  // 4 waves/block, EPW edges/wave
  edge_kernel<<<blocks, 256, 0, stream>>>(nf, ef, sh, ei, w1, b1, w2, b2,
                                          seg, cntb, out + (size_t)NN * 40);

  const int nblocks = (NN * 40 + 255) / 256;
  node_pass1<<<nblocks, 256, 0, stream>>>(seg, cntb, nf, pre, stats);
  node_pass2<<<nblocks, 256, 0, stream>>>(pre, stats, bnws, bnbs, bnwv, out);
}